// Round 2
// baseline (350.796 us; speedup 1.0000x reference)
//
#include <hip/hip_runtime.h>
#include <stdint.h>

typedef unsigned int u32;
typedef unsigned short u16;
typedef __attribute__((ext_vector_type(8))) _Float16 f16x8;
typedef __attribute__((ext_vector_type(16))) float f32x16;

#define DEVI __device__ __forceinline__

// ---------------- numeric helpers ----------------
DEVI u16 f2h(float f) {  // f32 -> f16 RNE (v_cvt_f16_f32)
  _Float16 h = (_Float16)f;
  return __builtin_bit_cast(u16, h);
}

// ---------------- ws layout (bytes) ----------------
#define WS_E16 0             // f16 E, [1024 rows][512]
#define WS_WT (1u << 20)     // f16 W1^T, [512 ch][2048 k]
#define WS_A (3u << 20)      // f32 a = E@Wa
#define WS_C (5u << 20)      // f32 c = E@Wb

// ---------------- kernel 0: fused E->f16 + out-zeroing (blocks 0..511) and
//                  W1 (2048x512 f32) -> W16T (512x2048 f16) (blocks 512..767)
__global__ void k_cvt(const float* __restrict__ E, u16* __restrict__ E16,
                      const float* __restrict__ W1, u16* __restrict__ WT,
                      float* __restrict__ outz) {
  __shared__ float tile[64][65];
  if (blockIdx.x < 512) {
    int i = (blockIdx.x * blockDim.x + threadIdx.x) * 4;
    float4 v = *(const float4*)(E + i);
    ushort4 o;
    o.x = f2h(v.x); o.y = f2h(v.y); o.z = f2h(v.z); o.w = f2h(v.w);
    *(ushort4*)(E16 + i) = o;
    // fold output zeroing (atomic-combine target): 256 blocks x 1024 floats
    if (blockIdx.x < 256) {
      float4 z; z.x = 0.f; z.y = 0.f; z.z = 0.f; z.w = 0.f;
      *(float4*)(outz + (blockIdx.x * blockDim.x + threadIdx.x) * 4) = z;
    }
    return;
  }
  int bid = blockIdx.x - 512;
  int t = threadIdx.x;
  int kBase = (bid & 31) * 64;   // 32 k-tiles
  int chBase = (bid >> 5) * 64;  // 8 ch-tiles
  int lr = t >> 4, lc = (t & 15) * 4;
  for (int rr = 0; rr < 4; rr++) {
    int kr = lr + rr * 16;
    float4 v = *(const float4*)(W1 + (kBase + kr) * 512 + chBase + lc);
    tile[kr][lc] = v.x; tile[kr][lc + 1] = v.y;
    tile[kr][lc + 2] = v.z; tile[kr][lc + 3] = v.w;
  }
  __syncthreads();
  int ch = t >> 2, ks = (t & 3) * 16;
  u32 w[8];
  for (int u = 0; u < 8; u++) {
    u16 lo = f2h(tile[ks + 2 * u][ch]);
    u16 hi = f2h(tile[ks + 2 * u + 1][ch]);
    w[u] = (u32)lo | ((u32)hi << 16);
  }
  u16* dst = WT + (chBase + ch) * 2048 + kBase + ks;
  uint4 s0; s0.x = w[0]; s0.y = w[1]; s0.z = w[2]; s0.w = w[3];
  uint4 s1; s1.x = w[4]; s1.y = w[5]; s1.z = w[6]; s1.w = w[7];
  *(uint4*)(dst) = s0;
  *(uint4*)(dst + 8) = s1;
}

// ---------------- kernel 1: a = E@Wa, c = E@Wb (f16 MFMA) -------------------
// Retiled 64x64 (R10: 128x128 grid 8x8 = 64 blocks -> only 25% of CUs busy).
// grid 16x16 = 256 blocks, 8KB LDS, acc 16 AGPR/wave. K-chunk order identical
// to the 128-tile version -> bitwise-identical Aw/Cw.
__global__ __launch_bounds__(256) void k_ac(const u16* __restrict__ E16,
                                            const u16* __restrict__ WT,
                                            float* __restrict__ Aw,
                                            float* __restrict__ Cw) {
  __shared__ __align__(16) char smem[8192];
  char* sA = smem;         // [64 rows][32 k] f16, swizzled
  char* sB = smem + 4096;  // [64 ch][32 k]
  const int tid = threadIdx.x;
  const int lane = tid & 63, wid = tid >> 6;
  const int wr2 = wid >> 1, wc2 = wid & 1;  // wave quadrant of the 64x64 tile
  const int n = lane & 31, q = lane >> 5;
  const int rowBase = blockIdx.y * 64;
  const int chBase = blockIdx.x * 64;
  const int halfOff = (chBase >= 512) ? 512 : 0;
  const int chSrc0 = chBase - halfOff;
  f32x16 acc;
  for (int e = 0; e < 16; e++) acc[e] = 0.f;
  const int srow = tid >> 2, spg = tid & 3;
  const int slg = spg ^ ((srow >> 1) & 3);
  for (int kc = 0; kc < 16; kc++) {
    const int k0 = kc * 32;
    __syncthreads();
    *(uint4*)(sA + srow * 64 + slg * 16) =
        *(const uint4*)(E16 + (rowBase + srow) * 512 + k0 + spg * 8);
    *(uint4*)(sB + srow * 64 + slg * 16) =
        *(const uint4*)(WT + (chSrc0 + srow) * 2048 + halfOff + k0 + spg * 8);
    __syncthreads();
    for (int ks = 0; ks < 2; ks++) {
      int kg = ks * 2 + q;
      int row = wr2 * 32 + n;
      int ch = wc2 * 32 + n;
      f16x8 af = *(const f16x8*)(sA + row * 64 + ((kg ^ ((row >> 1) & 3)) * 16));
      f16x8 bf = *(const f16x8*)(sB + ch * 64 + ((kg ^ ((ch >> 1) & 3)) * 16));
      acc = __builtin_amdgcn_mfma_f32_32x32x16_f16(af, bf, acc, 0, 0, 0);
    }
  }
  for (int r = 0; r < 16; r++) {
    int rowl = (r & 3) + 8 * (r >> 2) + 4 * q;  // C/D layout (m74/m101)
    int rowg = rowBase + wr2 * 32 + rowl;
    int chg = chBase + wc2 * 32 + n;
    float v = acc[r];
    if (chg < 512) Aw[rowg * 512 + chg] = v;
    else Cw[rowg * 512 + chg - 512] = v;
  }
}

// ---------------- kernel 2: pair kernel (f16, symmetric, barrier-free) -----
// R12: B tiles PRIVATIZED PER WAVE -> zero s_barrier in the main loop.
// Old geometry: wave = 4i x 16j x 128ch, B tile (16KB) shared by 4 waves ->
// 2 barriers per u/v pair = 32 barriers; barrier jitter + asm memory-clobber
// fences dominated the phase wall (MfmaUtil 34%, phase ~1600cy vs 512cy MFMA).
// New geometry: wave = 8i x 16j x 64ch (acc[4][2], still 128 AGPR). Each wave
// already LOADED its own 64-ch chunk (vInv has wid*64); now it also READS only
// that chunk, from a private 3x4KB rotating buffer (48KB total B, unchanged).
// Sync = per-wave s_waitcnt vmcnt only; e-tiles are read-only after prologue.
// Cost: A-frag formation redundancy 2x->4x (VALU pipe, overlaps MFMA).
// Arithmetic per (pair,ch) element has identical k-order -> same rounding.
#define EI_OFF 0             // 8 rows x 520 f16 (1040B) = 8320
#define EJ_OFF 8320          // 16 rows x 1040B = 16640 -> 24960
#define BB_OFF 24960         // 4 waves x 3 bufs x 4096 -> 74112
#define AJB_OFF 24960        // epilogue alias over B region (16*256*4 = 16KB)
#define CJB_OFF 41344        // epilogue alias (16KB)
#define W2S_OFF 74112        // 1024 -> 75136
#define RED_OFF 0            // epilogue alias over dead e-tiles (4608)
#define RED2_OFF 4608        // 4608 -> 9216 (< 24960, e-region)
#define SMEM2 75136

// per-wave waits: vmcnt counts THIS wave's global_load_lds (4 per tile)
#define WAITV4 asm volatile("s_waitcnt vmcnt(4)" ::: "memory")
#define WAITV0 asm volatile("s_waitcnt vmcnt(0)" ::: "memory")

// acc[4][2]=128 AGPR + ~110 arch VGPR <= 256: 2 waves/SIMD structural max.
__global__ __launch_bounds__(256, 2) void k_pair(
    const u16* __restrict__ E16, const u16* __restrict__ WT,
    const float* __restrict__ Aw, const float* __restrict__ Cw,
    const float* __restrict__ b1, const float* __restrict__ w2,
    const float* __restrict__ b2, float* __restrict__ out) {
  __shared__ __align__(16) char smem[SMEM2];
  const int tid = threadIdx.x;
  const int lane = tid & 63, wid = tid >> 6;  // wid = ch-quarter owner
  const int n = lane & 31, q = lane >> 5;
  const int bb = blockIdx.z;
  const int ch0 = blockIdx.y * 256;

  // invert triangular tile index: f = tj*(tj+1) + ti, ti in [0, 2*tj+2)
  int f = blockIdx.x;
  int tj = (int)((__builtin_sqrtf(4.0f * (float)f + 1.0f) - 1.0f) * 0.5f);
  while ((tj + 1) * (tj + 2) <= f) tj++;
  while (tj * (tj + 1) > f) tj--;
  const int ti = f - tj * (tj + 1);
  const int bi0 = ti * 8;
  const int bj0 = tj * 16;

  // loop-invariant per-lane prefetch offset; wave wid loads ch chunk
  // [wid*64, wid*64+64) (pre-swizzled k-group source, m173 pattern)
  const int pg = (lane & 3) ^ ((lane >> 3) & 3);
  const int vInv = (wid * 64 + (lane >> 2)) * 2048 + pg * 8;

  // async-stage B tile lk into PRIVATE buf nbuf (wave-local, no sharing);
  // k-col = 1024 + (lk>>1)*32 + (lk&1)*512
  auto prefetch_W = [&](int lk, int nbuf) {
    const int sOff = ch0 * 2048 + 1024 + ((lk >> 1) << 5) + ((lk & 1) << 9);
    const u16* g = WT + sOff + vInv;
    char* dstBase = smem + BB_OFF + wid * 12288 + nbuf * 4096;
#pragma unroll
    for (int t = 0; t < 4; t++)
      __builtin_amdgcn_global_load_lds(
          (const __attribute__((address_space(1))) void*)(g + t * 32768),
          (__attribute__((address_space(3))) void*)(dstBase + t * 1024), 16, 0, 0);
  };

  prefetch_W(0, 0);

  // stage e-tiles f16 (rows 0..7 = e_i, 8..23 = e_j), 520-elem stride
  for (int s = tid; s < 1536; s += 256) {
    int row = s >> 6, c16 = s & 63;
    int grow = (row < 8) ? (bi0 + row) : (bj0 + row - 8);
    const u16* src = E16 + (bb * 256 + grow) * 512 + c16 * 8;
    int off = (row < 8) ? (EI_OFF + (row * 520 + c16 * 8) * 2)
                        : (EJ_OFF + ((row - 8) * 520 + c16 * 8) * 2);
    *(uint4*)(smem + off) = *(const uint4*)src;
  }
  __syncthreads();  // e-tiles visible to all; drains prefetch(0) (vmcnt 0)
  prefetch_W(1, 1);

  // wave covers i-rows (n>>4) + 2*rb for rb=0..3 (all 8), j-rows n&15 (all 16)
  const u16* eip = (const u16*)(smem + EI_OFF) + (n >> 4) * 520;
  const u16* ejp = (const u16*)(smem + EJ_OFF) + (n & 15) * 520;
  const char* Bme = smem + BB_OFF + wid * 12288;

  f32x16 acc[4][2];
  for (int a = 0; a < 4; a++)
    for (int c = 0; c < 2; c++)
      for (int e = 0; e < 16; e++) acc[a][c][e] = 0.f;

  for (int m = 0; m < 16; m++) {
    const int dBase = m * 32;
    // ---- u-phase: private tile lk=2m in buf (2m)%3 ----
    WAITV4;  // own tile 2m landed; tile 2m+1 stays in flight
    if (m < 15) prefetch_W(2 * m + 2, (2 * m + 2) % 3);
    {
      const char* B2 = Bme + ((2 * m) % 3) * 4096;
#pragma unroll
      for (int ks = 0; ks < 2; ks++) {
        const int d0 = dBase + ks * 16 + q * 8;
        const int kg = ks * 2 + q;
        f16x8 eb = *(const f16x8*)(ejp + d0);
        f16x8 bfr[2];
#pragma unroll
        for (int cb = 0; cb < 2; cb++) {
          int ch = cb * 32 + n;
          bfr[cb] = *(const f16x8*)(B2 + ch * 64 + ((kg ^ ((ch >> 1) & 3)) * 16));
        }
#pragma unroll
        for (int rb = 0; rb < 4; rb++) {
          f16x8 ea = *(const f16x8*)(eip + rb * 1040 + d0);  // rows (n>>4)+2rb
          f16x8 u = ea * eb;  // v_pk_mul_f16
#pragma unroll
          for (int cb = 0; cb < 2; cb++)
            acc[rb][cb] = __builtin_amdgcn_mfma_f32_32x32x16_f16(
                u, bfr[cb], acc[rb][cb], 0, 0, 0);
        }
      }
    }
    // ---- v-phase: private tile lk=2m+1 in buf (2m+1)%3 ----
    if (m == 15) { WAITV0; } else { WAITV4; }
    if (m < 15) prefetch_W(2 * m + 3, (2 * m + 3) % 3);
    {
      const char* B2 = Bme + ((2 * m + 1) % 3) * 4096;
#pragma unroll
      for (int ks = 0; ks < 2; ks++) {
        const int d0 = dBase + ks * 16 + q * 8;
        const int kg = ks * 2 + q;
        f16x8 eb = *(const f16x8*)(ejp + d0);
        f16x8 bfr[2];
#pragma unroll
        for (int cb = 0; cb < 2; cb++) {
          int ch = cb * 32 + n;
          bfr[cb] = *(const f16x8*)(B2 + ch * 64 + ((kg ^ ((ch >> 1) & 3)) * 16));
        }
#pragma unroll
        for (int rb = 0; rb < 4; rb++) {
          f16x8 ea = *(const f16x8*)(eip + rb * 1040 + d0);
          f16x8 dd = ea - eb;
          f16x8 vv = __builtin_elementwise_max(dd, -dd);  // v_pk_max_f16
#pragma unroll
          for (int cb = 0; cb < 2; cb++)
            acc[rb][cb] = __builtin_amdgcn_mfma_f32_32x32x16_f16(
                vv, bfr[cb], acc[rb][cb], 0, 0, 0);
        }
      }
    }
  }

  // ---- epilogue: emit fwd (i,j) and transposed (j,i) partial scores ----
  __syncthreads();  // the ONLY main-path barrier: all waves done with B/e LDS
  {
    float b1v = b1[ch0 + tid];
    for (int j = 0; j < 16; j++) {
      int grow = (bb * 256 + bj0 + j) * 512 + ch0 + tid;
      *(float*)(smem + CJB_OFF + (j * 256 + tid) * 4) = Cw[grow] + b1v;
      *(float*)(smem + AJB_OFF + (j * 256 + tid) * 4) = Aw[grow] + b1v;
    }
    *(float*)(smem + W2S_OFF + tid * 4) = w2[ch0 + tid];
  }
  __syncthreads();

  float* RED = (float*)(smem + RED_OFF);
  float* RED2 = (float*)(smem + RED2_OFF);
  const float* CJB = (const float*)(smem + CJB_OFF);
  const float* AJB = (const float*)(smem + AJB_OFF);
  const float* W2S = (const float*)(smem + W2S_OFF);
  for (int rb = 0; rb < 4; rb++) {
    float av2[2][2], civ[2][2], w2v[2];
    int chls[2];
    for (int cb = 0; cb < 2; cb++) {
      int chl = wid * 64 + cb * 32 + n;
      chls[cb] = chl;
      w2v[cb] = W2S[chl];
      int irow = (bb * 256 + bi0 + rb * 2) * 512 + ch0 + chl;
      av2[cb][0] = Aw[irow];
      av2[cb][1] = Aw[irow + 512];
      civ[cb][0] = Cw[irow];
      civ[cb][1] = Cw[irow + 512];
    }
    for (int r = 0; r < 16; r++) {
      int rowl = (r & 3) + 8 * (r >> 2) + 4 * q;  // C/D layout (m74/m101)
      int j = rowl & 15;
      int hi = r >> 3;  // == rowl>>4: i-row parity within the rb pair
      float vf = 0.f, vt = 0.f;
      for (int cb = 0; cb < 2; cb++) {
        float base = acc[rb][cb][r];
        float hf = base + av2[cb][hi] + CJB[j * 256 + chls[cb]];
        if (hf > 0.f) vf += hf * w2v[cb];
        float ht = base + civ[cb][hi] + AJB[j * 256 + chls[cb]];
        if (ht > 0.f) vt += ht * w2v[cb];
      }
      vf += __shfl_xor(vf, 1); vt += __shfl_xor(vt, 1);
      vf += __shfl_xor(vf, 2); vt += __shfl_xor(vt, 2);
      vf += __shfl_xor(vf, 4); vt += __shfl_xor(vt, 4);
      vf += __shfl_xor(vf, 8); vt += __shfl_xor(vt, 8);
      if ((n & 15) == 0) {
        int p = (rb * 2 + hi) * 16 + j;  // pair index i*16+j
        int slot = p * 9 + wid * 2 + (n >> 4);
        RED[slot] = vf;
        RED2[slot] = vt;
      }
    }
  }

  __syncthreads();
  {
    int p = tid & 127;
    int gi = bi0 + (p >> 4), gj = bj0 + (p & 15);
    float half_b2 = 0.5f * b2[0];  // each ch-half block contributes half of b2
    if (tid < 128) {
      float s = half_b2;
      for (int u = 0; u < 8; u++) s += RED[p * 9 + u];
      if (gi <= gj) atomicAdd(out + (bb * 256 + gi) * 256 + gj, s);
    } else {
      float s = half_b2;
      for (int u = 0; u < 8; u++) s += RED2[p * 9 + u];
      if (gi < gj) atomicAdd(out + (bb * 256 + gj) * 256 + gi, s);
    }
  }
}

// ---------------- launcher ----------------
extern "C" void kernel_launch(void* const* d_in, const int* in_sizes, int n_in,
                              void* d_out, int out_size, void* d_ws, size_t ws_size,
                              hipStream_t stream) {
  const float* E = (const float*)d_in[0];
  const float* W1 = (const float*)d_in[1];
  const float* b1 = (const float*)d_in[2];
  const float* W2 = (const float*)d_in[3];
  const float* b2 = (const float*)d_in[4];
  float* out = (float*)d_out;
  char* ws = (char*)d_ws;
  u16* E16 = (u16*)(ws + WS_E16);
  u16* WT = (u16*)(ws + WS_WT);
  float* Aw = (float*)(ws + WS_A);
  float* Cw = (float*)(ws + WS_C);

  // k_cvt also zeroes out (atomic-combine target) — no separate memset
  hipLaunchKernelGGL(k_cvt, dim3(768), dim3(256), 0, stream, E, E16, W1, WT, out);
  hipLaunchKernelGGL(k_ac, dim3(16, 16), dim3(256), 0, stream, E16, WT, Aw, Cw);
  // 272 = # of 8x16 pair-tiles intersecting the upper triangle (tj*(tj+1)+ti)
  hipLaunchKernelGGL(k_pair, dim3(272, 2, 4), dim3(256), 0, stream,
                     E16, WT, Aw, Cw, b1, W2, b2, out);
}

// Round 3
// 281.981 us; speedup vs baseline: 1.2440x; 1.2440x over previous
//
#include <hip/hip_runtime.h>
#include <stdint.h>

typedef unsigned int u32;
typedef unsigned short u16;
typedef __attribute__((ext_vector_type(8))) _Float16 f16x8;
typedef __attribute__((ext_vector_type(16))) float f32x16;

#define DEVI __device__ __forceinline__

// ---------------- numeric helpers ----------------
DEVI u16 f2h(float f) {  // f32 -> f16 RNE (v_cvt_f16_f32)
  _Float16 h = (_Float16)f;
  return __builtin_bit_cast(u16, h);
}

// ---------------- ws layout (bytes) ----------------
#define WS_E16 0             // f16 E, [1024 rows][512]
#define WS_WT (1u << 20)     // f16 W1^T, [512 ch][2048 k]
#define WS_A (3u << 20)      // f32 a = E@Wa
#define WS_C (5u << 20)      // f32 c = E@Wb

// ---------------- kernel 0: fused E->f16 + out-zeroing (blocks 0..511) and
//                  W1 (2048x512 f32) -> W16T (512x2048 f16) (blocks 512..767)
__global__ void k_cvt(const float* __restrict__ E, u16* __restrict__ E16,
                      const float* __restrict__ W1, u16* __restrict__ WT,
                      float* __restrict__ outz) {
  __shared__ float tile[64][65];
  if (blockIdx.x < 512) {
    int i = (blockIdx.x * blockDim.x + threadIdx.x) * 4;
    float4 v = *(const float4*)(E + i);
    ushort4 o;
    o.x = f2h(v.x); o.y = f2h(v.y); o.z = f2h(v.z); o.w = f2h(v.w);
    *(ushort4*)(E16 + i) = o;
    // fold output zeroing (atomic-combine target): 256 blocks x 1024 floats
    if (blockIdx.x < 256) {
      float4 z; z.x = 0.f; z.y = 0.f; z.z = 0.f; z.w = 0.f;
      *(float4*)(outz + (blockIdx.x * blockDim.x + threadIdx.x) * 4) = z;
    }
    return;
  }
  int bid = blockIdx.x - 512;
  int t = threadIdx.x;
  int kBase = (bid & 31) * 64;   // 32 k-tiles
  int chBase = (bid >> 5) * 64;  // 8 ch-tiles
  int lr = t >> 4, lc = (t & 15) * 4;
  for (int rr = 0; rr < 4; rr++) {
    int kr = lr + rr * 16;
    float4 v = *(const float4*)(W1 + (kBase + kr) * 512 + chBase + lc);
    tile[kr][lc] = v.x; tile[kr][lc + 1] = v.y;
    tile[kr][lc + 2] = v.z; tile[kr][lc + 3] = v.w;
  }
  __syncthreads();
  int ch = t >> 2, ks = (t & 3) * 16;
  u32 w[8];
  for (int u = 0; u < 8; u++) {
    u16 lo = f2h(tile[ks + 2 * u][ch]);
    u16 hi = f2h(tile[ks + 2 * u + 1][ch]);
    w[u] = (u32)lo | ((u32)hi << 16);
  }
  u16* dst = WT + (chBase + ch) * 2048 + kBase + ks;
  uint4 s0; s0.x = w[0]; s0.y = w[1]; s0.z = w[2]; s0.w = w[3];
  uint4 s1; s1.x = w[4]; s1.y = w[5]; s1.z = w[6]; s1.w = w[7];
  *(uint4*)(dst) = s0;
  *(uint4*)(dst + 8) = s1;
}

// ---------------- kernel 1: a = E@Wa, c = E@Wb (f16 MFMA) -------------------
// Retiled 64x64 (R10: 128x128 grid 8x8 = 64 blocks -> only 25% of CUs busy).
// grid 16x16 = 256 blocks, 8KB LDS, acc 16 AGPR/wave. K-chunk order identical
// to the 128-tile version -> bitwise-identical Aw/Cw.
__global__ __launch_bounds__(256) void k_ac(const u16* __restrict__ E16,
                                            const u16* __restrict__ WT,
                                            float* __restrict__ Aw,
                                            float* __restrict__ Cw) {
  __shared__ __align__(16) char smem[8192];
  char* sA = smem;         // [64 rows][32 k] f16, swizzled
  char* sB = smem + 4096;  // [64 ch][32 k]
  const int tid = threadIdx.x;
  const int lane = tid & 63, wid = tid >> 6;
  const int wr2 = wid >> 1, wc2 = wid & 1;  // wave quadrant of the 64x64 tile
  const int n = lane & 31, q = lane >> 5;
  const int rowBase = blockIdx.y * 64;
  const int chBase = blockIdx.x * 64;
  const int halfOff = (chBase >= 512) ? 512 : 0;
  const int chSrc0 = chBase - halfOff;
  f32x16 acc;
  for (int e = 0; e < 16; e++) acc[e] = 0.f;
  const int srow = tid >> 2, spg = tid & 3;
  const int slg = spg ^ ((srow >> 1) & 3);
  for (int kc = 0; kc < 16; kc++) {
    const int k0 = kc * 32;
    __syncthreads();
    *(uint4*)(sA + srow * 64 + slg * 16) =
        *(const uint4*)(E16 + (rowBase + srow) * 512 + k0 + spg * 8);
    *(uint4*)(sB + srow * 64 + slg * 16) =
        *(const uint4*)(WT + (chSrc0 + srow) * 2048 + halfOff + k0 + spg * 8);
    __syncthreads();
    for (int ks = 0; ks < 2; ks++) {
      int kg = ks * 2 + q;
      int row = wr2 * 32 + n;
      int ch = wc2 * 32 + n;
      f16x8 af = *(const f16x8*)(sA + row * 64 + ((kg ^ ((row >> 1) & 3)) * 16));
      f16x8 bf = *(const f16x8*)(sB + ch * 64 + ((kg ^ ((ch >> 1) & 3)) * 16));
      acc = __builtin_amdgcn_mfma_f32_32x32x16_f16(af, bf, acc, 0, 0, 0);
    }
  }
  for (int r = 0; r < 16; r++) {
    int rowl = (r & 3) + 8 * (r >> 2) + 4 * q;  // C/D layout (m74/m101)
    int rowg = rowBase + wr2 * 32 + rowl;
    int chg = chBase + wc2 * 32 + n;
    float v = acc[r];
    if (chg < 512) Aw[rowg * 512 + chg] = v;
    else Cw[rowg * 512 + chg - 512] = v;
  }
}

// ---------------- kernel 2: pair kernel (f16, symmetric, barrier-free) -----
// R12: B tiles PRIVATIZED PER WAVE -> zero s_barrier in the main loop.
// Wave = 8i x 16j x 64ch (acc[4][2], 128 AGPR); each wave loads AND reads only
// its own 64-ch chunk from a private 3x4KB rotating buffer. Sync = per-wave
// s_waitcnt vmcnt only; e-tiles read-only after prologue.
// R13 FIX: R12 regressed (303us) because the epilogue indexed acc[rb][cb][r]
// from rolled loops -> runtime indices -> compiler demoted the whole acc
// array to scratch (rule #20). Evidence: WRITE_SIZE 3MB->587MB (= 2176 blk x
// 256 thr x ~1KB scratch churn), FETCH +176MB, kernel HBM-bound at 2.66TB/s.
// Fix: #pragma unroll on EVERY epilogue loop touching acc -> all indices
// compile-time constant -> acc stays in AGPRs.
#define EI_OFF 0             // 8 rows x 520 f16 (1040B) = 8320
#define EJ_OFF 8320          // 16 rows x 1040B = 16640 -> 24960
#define BB_OFF 24960         // 4 waves x 3 bufs x 4096 -> 74112
#define AJB_OFF 24960        // epilogue alias over B region (16*256*4 = 16KB)
#define CJB_OFF 41344        // epilogue alias (16KB)
#define W2S_OFF 74112        // 1024 -> 75136
#define RED_OFF 0            // epilogue alias over dead e-tiles (4608)
#define RED2_OFF 4608        // 4608 -> 9216 (< 24960, e-region)
#define SMEM2 75136

// per-wave waits: vmcnt counts THIS wave's global_load_lds (4 per tile)
#define WAITV4 asm volatile("s_waitcnt vmcnt(4)" ::: "memory")
#define WAITV0 asm volatile("s_waitcnt vmcnt(0)" ::: "memory")

// acc[4][2]=128 AGPR + ~116 arch VGPR <= 256: 2 waves/SIMD structural max.
__global__ __launch_bounds__(256, 2) void k_pair(
    const u16* __restrict__ E16, const u16* __restrict__ WT,
    const float* __restrict__ Aw, const float* __restrict__ Cw,
    const float* __restrict__ b1, const float* __restrict__ w2,
    const float* __restrict__ b2, float* __restrict__ out) {
  __shared__ __align__(16) char smem[SMEM2];
  const int tid = threadIdx.x;
  const int lane = tid & 63, wid = tid >> 6;  // wid = ch-quarter owner
  const int n = lane & 31, q = lane >> 5;
  const int bb = blockIdx.z;
  const int ch0 = blockIdx.y * 256;

  // invert triangular tile index: f = tj*(tj+1) + ti, ti in [0, 2*tj+2)
  int f = blockIdx.x;
  int tj = (int)((__builtin_sqrtf(4.0f * (float)f + 1.0f) - 1.0f) * 0.5f);
  while ((tj + 1) * (tj + 2) <= f) tj++;
  while (tj * (tj + 1) > f) tj--;
  const int ti = f - tj * (tj + 1);
  const int bi0 = ti * 8;
  const int bj0 = tj * 16;

  // loop-invariant per-lane prefetch offset; wave wid loads ch chunk
  // [wid*64, wid*64+64) (pre-swizzled k-group source, m173 pattern)
  const int pg = (lane & 3) ^ ((lane >> 3) & 3);
  const int vInv = (wid * 64 + (lane >> 2)) * 2048 + pg * 8;

  // async-stage B tile lk into PRIVATE buf nbuf (wave-local, no sharing);
  // k-col = 1024 + (lk>>1)*32 + (lk&1)*512
  auto prefetch_W = [&](int lk, int nbuf) {
    const int sOff = ch0 * 2048 + 1024 + ((lk >> 1) << 5) + ((lk & 1) << 9);
    const u16* g = WT + sOff + vInv;
    char* dstBase = smem + BB_OFF + wid * 12288 + nbuf * 4096;
#pragma unroll
    for (int t = 0; t < 4; t++)
      __builtin_amdgcn_global_load_lds(
          (const __attribute__((address_space(1))) void*)(g + t * 32768),
          (__attribute__((address_space(3))) void*)(dstBase + t * 1024), 16, 0, 0);
  };

  prefetch_W(0, 0);

  // stage e-tiles f16 (rows 0..7 = e_i, 8..23 = e_j), 520-elem stride
  for (int s = tid; s < 1536; s += 256) {
    int row = s >> 6, c16 = s & 63;
    int grow = (row < 8) ? (bi0 + row) : (bj0 + row - 8);
    const u16* src = E16 + (bb * 256 + grow) * 512 + c16 * 8;
    int off = (row < 8) ? (EI_OFF + (row * 520 + c16 * 8) * 2)
                        : (EJ_OFF + ((row - 8) * 520 + c16 * 8) * 2);
    *(uint4*)(smem + off) = *(const uint4*)src;
  }
  __syncthreads();  // e-tiles visible to all; drains prefetch(0) (vmcnt 0)
  prefetch_W(1, 1);

  // wave covers i-rows (n>>4) + 2*rb for rb=0..3 (all 8), j-rows n&15 (all 16)
  const u16* eip = (const u16*)(smem + EI_OFF) + (n >> 4) * 520;
  const u16* ejp = (const u16*)(smem + EJ_OFF) + (n & 15) * 520;
  const char* Bme = smem + BB_OFF + wid * 12288;

  f32x16 acc[4][2];
#pragma unroll
  for (int a = 0; a < 4; a++)
#pragma unroll
    for (int c = 0; c < 2; c++)
#pragma unroll
      for (int e = 0; e < 16; e++) acc[a][c][e] = 0.f;

  for (int m = 0; m < 16; m++) {
    const int dBase = m * 32;
    // ---- u-phase: private tile lk=2m in buf (2m)%3 ----
    WAITV4;  // own tile 2m landed; tile 2m+1 stays in flight
    if (m < 15) prefetch_W(2 * m + 2, (2 * m + 2) % 3);
    {
      const char* B2 = Bme + ((2 * m) % 3) * 4096;
#pragma unroll
      for (int ks = 0; ks < 2; ks++) {
        const int d0 = dBase + ks * 16 + q * 8;
        const int kg = ks * 2 + q;
        f16x8 eb = *(const f16x8*)(ejp + d0);
        f16x8 bfr[2];
#pragma unroll
        for (int cb = 0; cb < 2; cb++) {
          int ch = cb * 32 + n;
          bfr[cb] = *(const f16x8*)(B2 + ch * 64 + ((kg ^ ((ch >> 1) & 3)) * 16));
        }
#pragma unroll
        for (int rb = 0; rb < 4; rb++) {
          f16x8 ea = *(const f16x8*)(eip + rb * 1040 + d0);  // rows (n>>4)+2rb
          f16x8 u = ea * eb;  // v_pk_mul_f16
#pragma unroll
          for (int cb = 0; cb < 2; cb++)
            acc[rb][cb] = __builtin_amdgcn_mfma_f32_32x32x16_f16(
                u, bfr[cb], acc[rb][cb], 0, 0, 0);
        }
      }
    }
    // ---- v-phase: private tile lk=2m+1 in buf (2m+1)%3 ----
    if (m == 15) { WAITV0; } else { WAITV4; }
    if (m < 15) prefetch_W(2 * m + 3, (2 * m + 3) % 3);
    {
      const char* B2 = Bme + ((2 * m + 1) % 3) * 4096;
#pragma unroll
      for (int ks = 0; ks < 2; ks++) {
        const int d0 = dBase + ks * 16 + q * 8;
        const int kg = ks * 2 + q;
        f16x8 eb = *(const f16x8*)(ejp + d0);
        f16x8 bfr[2];
#pragma unroll
        for (int cb = 0; cb < 2; cb++) {
          int ch = cb * 32 + n;
          bfr[cb] = *(const f16x8*)(B2 + ch * 64 + ((kg ^ ((ch >> 1) & 3)) * 16));
        }
#pragma unroll
        for (int rb = 0; rb < 4; rb++) {
          f16x8 ea = *(const f16x8*)(eip + rb * 1040 + d0);
          f16x8 dd = ea - eb;
          f16x8 vv = __builtin_elementwise_max(dd, -dd);  // v_pk_max_f16
#pragma unroll
          for (int cb = 0; cb < 2; cb++)
            acc[rb][cb] = __builtin_amdgcn_mfma_f32_32x32x16_f16(
                vv, bfr[cb], acc[rb][cb], 0, 0, 0);
        }
      }
    }
  }

  // ---- epilogue: emit fwd (i,j) and transposed (j,i) partial scores ----
  __syncthreads();  // the ONLY main-path barrier: all waves done with B/e LDS
  {
    float b1v = b1[ch0 + tid];
    for (int j = 0; j < 16; j++) {
      int grow = (bb * 256 + bj0 + j) * 512 + ch0 + tid;
      *(float*)(smem + CJB_OFF + (j * 256 + tid) * 4) = Cw[grow] + b1v;
      *(float*)(smem + AJB_OFF + (j * 256 + tid) * 4) = Aw[grow] + b1v;
    }
    *(float*)(smem + W2S_OFF + tid * 4) = w2[ch0 + tid];
  }
  __syncthreads();

  float* RED = (float*)(smem + RED_OFF);
  float* RED2 = (float*)(smem + RED2_OFF);
  const float* CJB = (const float*)(smem + CJB_OFF);
  const float* AJB = (const float*)(smem + AJB_OFF);
  const float* W2S = (const float*)(smem + W2S_OFF);
  // R13: all loops touching acc are force-unrolled -> static acc indices
  // (rule #20: runtime-indexed ext_vector arrays go to scratch).
#pragma unroll
  for (int rb = 0; rb < 4; rb++) {
    float av2[2][2], civ[2][2], w2v[2];
    int chls[2];
#pragma unroll
    for (int cb = 0; cb < 2; cb++) {
      int chl = wid * 64 + cb * 32 + n;
      chls[cb] = chl;
      w2v[cb] = W2S[chl];
      int irow = (bb * 256 + bi0 + rb * 2) * 512 + ch0 + chl;
      av2[cb][0] = Aw[irow];
      av2[cb][1] = Aw[irow + 512];
      civ[cb][0] = Cw[irow];
      civ[cb][1] = Cw[irow + 512];
    }
#pragma unroll
    for (int r = 0; r < 16; r++) {
      int rowl = (r & 3) + 8 * (r >> 2) + 4 * q;  // C/D layout (m74/m101)
      int j = rowl & 15;
      int hi = r >> 3;  // == rowl>>4: i-row parity within the rb pair
      float vf = 0.f, vt = 0.f;
#pragma unroll
      for (int cb = 0; cb < 2; cb++) {
        float base = acc[rb][cb][r];
        float hf = base + av2[cb][hi] + CJB[j * 256 + chls[cb]];
        if (hf > 0.f) vf += hf * w2v[cb];
        float ht = base + civ[cb][hi] + AJB[j * 256 + chls[cb]];
        if (ht > 0.f) vt += ht * w2v[cb];
      }
      vf += __shfl_xor(vf, 1); vt += __shfl_xor(vt, 1);
      vf += __shfl_xor(vf, 2); vt += __shfl_xor(vt, 2);
      vf += __shfl_xor(vf, 4); vt += __shfl_xor(vt, 4);
      vf += __shfl_xor(vf, 8); vt += __shfl_xor(vt, 8);
      if ((n & 15) == 0) {
        int p = (rb * 2 + hi) * 16 + j;  // pair index i*16+j
        int slot = p * 9 + wid * 2 + (n >> 4);
        RED[slot] = vf;
        RED2[slot] = vt;
      }
    }
  }

  __syncthreads();
  {
    int p = tid & 127;
    int gi = bi0 + (p >> 4), gj = bj0 + (p & 15);
    float half_b2 = 0.5f * b2[0];  // each ch-half block contributes half of b2
    if (tid < 128) {
      float s = half_b2;
      for (int u = 0; u < 8; u++) s += RED[p * 9 + u];
      if (gi <= gj) atomicAdd(out + (bb * 256 + gi) * 256 + gj, s);
    } else {
      float s = half_b2;
      for (int u = 0; u < 8; u++) s += RED2[p * 9 + u];
      if (gi < gj) atomicAdd(out + (bb * 256 + gj) * 256 + gi, s);
    }
  }
}

// ---------------- launcher ----------------
extern "C" void kernel_launch(void* const* d_in, const int* in_sizes, int n_in,
                              void* d_out, int out_size, void* d_ws, size_t ws_size,
                              hipStream_t stream) {
  const float* E = (const float*)d_in[0];
  const float* W1 = (const float*)d_in[1];
  const float* b1 = (const float*)d_in[2];
  const float* W2 = (const float*)d_in[3];
  const float* b2 = (const float*)d_in[4];
  float* out = (float*)d_out;
  char* ws = (char*)d_ws;
  u16* E16 = (u16*)(ws + WS_E16);
  u16* WT = (u16*)(ws + WS_WT);
  float* Aw = (float*)(ws + WS_A);
  float* Cw = (float*)(ws + WS_C);

  // k_cvt also zeroes out (atomic-combine target) — no separate memset
  hipLaunchKernelGGL(k_cvt, dim3(768), dim3(256), 0, stream, E, E16, W1, WT, out);
  hipLaunchKernelGGL(k_ac, dim3(16, 16), dim3(256), 0, stream, E16, WT, Aw, Cw);
  // 272 = # of 8x16 pair-tiles intersecting the upper triangle (tj*(tj+1)+ti)
  hipLaunchKernelGGL(k_pair, dim3(272, 2, 4), dim3(256), 0, stream,
                     E16, WT, Aw, Cw, b1, W2, b2, out);
}

// Round 4
// 257.905 us; speedup vs baseline: 1.3602x; 1.0934x over previous
//
#include <hip/hip_runtime.h>
#include <stdint.h>

typedef unsigned int u32;
typedef unsigned short u16;
typedef __attribute__((ext_vector_type(8))) _Float16 f16x8;
typedef __attribute__((ext_vector_type(16))) float f32x16;

#define DEVI __device__ __forceinline__

// ---------------- numeric helpers ----------------
DEVI u16 f2h(float f) {  // f32 -> f16 RNE (v_cvt_f16_f32)
  _Float16 h = (_Float16)f;
  return __builtin_bit_cast(u16, h);
}

// ---------------- ws layout (bytes) ----------------
#define WS_E16 0             // f16 E, [1024 rows][512]
#define WS_WT (1u << 20)     // f16 W1^T, [512 ch][2048 k] (k_ac reads k<1024)
#define WS_A (3u << 20)      // f32 a = E@Wa
#define WS_C (5u << 20)      // f32 c = E@Wb
#define WS_WF (7u << 20)     // f16 Wc/Wd fragment-major, 1MB (k_pair B regs)

// ---------------- kernel 0: fused E->f16 + out-zeroing (blocks 0..511) and
//                  W1 (2048x512 f32) -> W16T (512x2048 f16) + WF fragment-major
//                  (blocks 512..767)
__global__ void k_cvt(const float* __restrict__ E, u16* __restrict__ E16,
                      const float* __restrict__ W1, u16* __restrict__ WT,
                      u16* __restrict__ WFo, float* __restrict__ outz) {
  __shared__ float tile[64][65];
  if (blockIdx.x < 512) {
    int i = (blockIdx.x * blockDim.x + threadIdx.x) * 4;
    float4 v = *(const float4*)(E + i);
    ushort4 o;
    o.x = f2h(v.x); o.y = f2h(v.y); o.z = f2h(v.z); o.w = f2h(v.w);
    *(ushort4*)(E16 + i) = o;
    // fold output zeroing (atomic-combine target): 256 blocks x 1024 floats
    if (blockIdx.x < 256) {
      float4 z; z.x = 0.f; z.y = 0.f; z.z = 0.f; z.w = 0.f;
      *(float4*)(outz + (blockIdx.x * blockDim.x + threadIdx.x) * 4) = z;
    }
    return;
  }
  int bid = blockIdx.x - 512;
  int t = threadIdx.x;
  int kBase = (bid & 31) * 64;   // 32 k-tiles
  int chBase = (bid >> 5) * 64;  // 8 ch-tiles
  int lr = t >> 4, lc = (t & 15) * 4;
  for (int rr = 0; rr < 4; rr++) {
    int kr = lr + rr * 16;
    float4 v = *(const float4*)(W1 + (kBase + kr) * 512 + chBase + lc);
    tile[kr][lc] = v.x; tile[kr][lc + 1] = v.y;
    tile[kr][lc + 2] = v.z; tile[kr][lc + 3] = v.w;
  }
  __syncthreads();
  int ch = t >> 2, ks = (t & 3) * 16;
  u32 w[8];
  for (int u = 0; u < 8; u++) {
    u16 lo = f2h(tile[ks + 2 * u][ch]);
    u16 hi = f2h(tile[ks + 2 * u + 1][ch]);
    w[u] = (u32)lo | ((u32)hi << 16);
  }
  u16* dst = WT + (chBase + ch) * 2048 + kBase + ks;
  uint4 s0; s0.x = w[0]; s0.y = w[1]; s0.z = w[2]; s0.w = w[3];
  uint4 s1; s1.x = w[4]; s1.y = w[5]; s1.z = w[6]; s1.w = w[7];
  *(uint4*)(dst) = s0;
  *(uint4*)(dst + 8) = s1;

  // ---- WF emission (Wc/Wd only): fragment-major layout so k_pair can load
  // B-fragments global->VGPR fully coalesced.
  // WF byte offset = ((cq*32 + lk)*4 + f)*1024 + lane*16, f = ks*2 + cb.
  // Fragment value = W1[k0 + kf + e][cq*64 + cb*32 + (lane&31)], e=0..7,
  // kf = (ks*2 + (lane>>5))*8 — identical halves to the old LDS bfr path.
  if (kBase >= 1024) {
    int fidx = (t >> 6) & 3;  // frag f
    int l = t & 63;           // lane
    int cbl = (fidx & 1) * 32 + (l & 31);
    int kf = ((fidx >> 1) * 2 + (l >> 5)) * 8;
    int cqv = bid >> 5;
#pragma unroll
    for (int s = 0; s < 2; s++) {
      int k0 = kBase + s * 32;  // == tile k-base of lk (verified mapping)
      int lk = (k0 < 1536) ? (((k0 - 1024) >> 5) * 2)
                           : (((k0 - 1536) >> 5) * 2 + 1);
      int klocal = s * 32 + kf;
      u32 wv[4];
#pragma unroll
      for (int u2 = 0; u2 < 4; u2++) {
        u16 lo = f2h(tile[klocal + 2 * u2][cbl]);
        u16 hi = f2h(tile[klocal + 2 * u2 + 1][cbl]);
        wv[u2] = (u32)lo | ((u32)hi << 16);
      }
      uint4 st; st.x = wv[0]; st.y = wv[1]; st.z = wv[2]; st.w = wv[3];
      *(uint4*)((char*)WFo + (((cqv * 32 + lk) * 4 + fidx) * 1024 + l * 16)) = st;
    }
  }
}

// ---------------- kernel 1: a = E@Wa, c = E@Wb (f16 MFMA) -------------------
// Retiled 64x64 (R10: 128x128 grid 8x8 = 64 blocks -> only 25% of CUs busy).
// grid 16x16 = 256 blocks, 8KB LDS, acc 16 AGPR/wave. K-chunk order identical
// to the 128-tile version -> bitwise-identical Aw/Cw.
__global__ __launch_bounds__(256) void k_ac(const u16* __restrict__ E16,
                                            const u16* __restrict__ WT,
                                            float* __restrict__ Aw,
                                            float* __restrict__ Cw) {
  __shared__ __align__(16) char smem[8192];
  char* sA = smem;         // [64 rows][32 k] f16, swizzled
  char* sB = smem + 4096;  // [64 ch][32 k]
  const int tid = threadIdx.x;
  const int lane = tid & 63, wid = tid >> 6;
  const int wr2 = wid >> 1, wc2 = wid & 1;  // wave quadrant of the 64x64 tile
  const int n = lane & 31, q = lane >> 5;
  const int rowBase = blockIdx.y * 64;
  const int chBase = blockIdx.x * 64;
  const int halfOff = (chBase >= 512) ? 512 : 0;
  const int chSrc0 = chBase - halfOff;
  f32x16 acc;
  for (int e = 0; e < 16; e++) acc[e] = 0.f;
  const int srow = tid >> 2, spg = tid & 3;
  const int slg = spg ^ ((srow >> 1) & 3);
  for (int kc = 0; kc < 16; kc++) {
    const int k0 = kc * 32;
    __syncthreads();
    *(uint4*)(sA + srow * 64 + slg * 16) =
        *(const uint4*)(E16 + (rowBase + srow) * 512 + k0 + spg * 8);
    *(uint4*)(sB + srow * 64 + slg * 16) =
        *(const uint4*)(WT + (chSrc0 + srow) * 2048 + halfOff + k0 + spg * 8);
    __syncthreads();
    for (int ks = 0; ks < 2; ks++) {
      int kg = ks * 2 + q;
      int row = wr2 * 32 + n;
      int ch = wc2 * 32 + n;
      f16x8 af = *(const f16x8*)(sA + row * 64 + ((kg ^ ((row >> 1) & 3)) * 16));
      f16x8 bf = *(const f16x8*)(sB + ch * 64 + ((kg ^ ((ch >> 1) & 3)) * 16));
      acc = __builtin_amdgcn_mfma_f32_32x32x16_f16(af, bf, acc, 0, 0, 0);
    }
  }
  for (int r = 0; r < 16; r++) {
    int rowl = (r & 3) + 8 * (r >> 2) + 4 * q;  // C/D layout (m74/m101)
    int rowg = rowBase + wr2 * 32 + rowl;
    int chg = chBase + wc2 * 32 + n;
    float v = acc[r];
    if (chg < 512) Aw[rowg * 512 + chg] = v;
    else Cw[rowg * 512 + chg - 512] = v;
  }
}

// ---------------- kernel 2: pair kernel (f16, symmetric, B in registers) ----
// R14: B-fragments now load global->VGPR from the fragment-major WF buffer
// (values bit-identical to the old LDS bfr path). Rationale: R13 counters put
// the LDS pipe as the most-loaded resource (8 waves/CU x ~18 LDS ops/phase
// x ~12cyc > MFMA 1034cyc/SIMD); the expensive ops were the full-bandwidth B
// ds_reads + global_load_lds writes. e-reads are mostly same-address
// broadcasts (cheap). Now: LDS holds ONLY e-tiles; B = 4 coalesced
// global_load_dwordx4/tile/wave into a bu/bv double buffer (WAR ordering +
// counted vmcnt handled by the compiler via register deps — no asm, no
// barriers). Wave = 8i x 16j x 64ch (acc[4][2], 128 AGPR), exclusive ch
// chunk -> B read redundancy 1x (1.1GB from L2 ~ 32us, hidden under MFMA).
// k-order unchanged -> bitwise-identical acc.
#define EI_OFF 0             // 8 rows x 520 f16 (1040B) = 8320
#define EJ_OFF 8320          // 16 rows x 1040B = 16640 -> 24960
#define RED_OFF 0            // epilogue alias over dead e-tiles (4608)
#define RED2_OFF 4608        // 4608 -> 9216
#define AJB_OFF 9216         // 16*256*4 = 16384 -> 25600 (e-region dead)
#define CJB_OFF 25600        // 16KB -> 41984
#define W2S_OFF 41984        // 1024 -> 43008
#define SMEM2 43008

// acc[4][2]=128 AGPR + bu/bv 32 + ~80 arch VGPR <= 256: 2 waves/SIMD max.
__global__ __launch_bounds__(256, 2) void k_pair(
    const u16* __restrict__ E16, const u16* __restrict__ WF,
    const float* __restrict__ Aw, const float* __restrict__ Cw,
    const float* __restrict__ b1, const float* __restrict__ w2,
    const float* __restrict__ b2, float* __restrict__ out) {
  __shared__ __align__(16) char smem[SMEM2];
  const int tid = threadIdx.x;
  const int lane = tid & 63, wid = tid >> 6;  // wid = ch-quarter owner
  const int n = lane & 31, q = lane >> 5;
  const int bb = blockIdx.z;
  const int ch0 = blockIdx.y * 256;

  // invert triangular tile index: f = tj*(tj+1) + ti, ti in [0, 2*tj+2)
  int f = blockIdx.x;
  int tj = (int)((__builtin_sqrtf(4.0f * (float)f + 1.0f) - 1.0f) * 0.5f);
  while ((tj + 1) * (tj + 2) <= f) tj++;
  while (tj * (tj + 1) > f) tj--;
  const int ti = f - tj * (tj + 1);
  const int bi0 = ti * 8;
  const int bj0 = tj * 16;

  // fragment-major B pointer for this wave's exclusive 64-ch chunk
  const int cq = blockIdx.y * 4 + wid;  // ch-quarter 0..7
  const f16x8* wfp = (const f16x8*)WF + cq * 8192 + lane;
  const f16x8* wfu = wfp;        // tile lk=0
  const f16x8* wfv = wfp + 256;  // tile lk=1

  f16x8 bu[4], bv[4];  // frag f = ks*2 + cb
  auto loadB = [&](f16x8 (&b)[4], const f16x8* p) {
#pragma unroll
    for (int f2 = 0; f2 < 4; f2++) b[f2] = p[f2 * 64];  // imm offsets 0..3KB
  };

  loadB(bu, wfu);  // tile 0 in flight

  // stage e-tiles f16 (rows 0..7 = e_i, 8..23 = e_j), 520-elem stride
  for (int s = tid; s < 1536; s += 256) {
    int row = s >> 6, c16 = s & 63;
    int grow = (row < 8) ? (bi0 + row) : (bj0 + row - 8);
    const u16* src = E16 + (bb * 256 + grow) * 512 + c16 * 8;
    int off = (row < 8) ? (EI_OFF + (row * 520 + c16 * 8) * 2)
                        : (EJ_OFF + ((row - 8) * 520 + c16 * 8) * 2);
    *(uint4*)(smem + off) = *(const uint4*)src;
  }
  __syncthreads();  // e-tiles visible to all waves
  loadB(bv, wfv);   // tile 1 in flight

  // wave covers i-rows (n>>4)+2*rb for rb=0..3 (all 8), j-rows n&15 (all 16)
  const u16* eip = (const u16*)(smem + EI_OFF) + (n >> 4) * 520;
  const u16* ejp = (const u16*)(smem + EJ_OFF) + (n & 15) * 520;

  f32x16 acc[4][2];
#pragma unroll
  for (int a = 0; a < 4; a++)
#pragma unroll
    for (int c = 0; c < 2; c++)
#pragma unroll
      for (int e = 0; e < 16; e++) acc[a][c][e] = 0.f;

  for (int m = 0; m < 16; m++) {
    const int dBase = m * 32;
    // ---- u-phase: consume bu (tile lk=2m) ----
#pragma unroll
    for (int ks = 0; ks < 2; ks++) {
      const int d0 = dBase + ks * 16 + q * 8;
      f16x8 eb = *(const f16x8*)(ejp + d0);
#pragma unroll
      for (int rb = 0; rb < 4; rb++) {
        f16x8 ea = *(const f16x8*)(eip + rb * 1040 + d0);  // rows (n>>4)+2rb
        f16x8 u = ea * eb;  // v_pk_mul_f16
#pragma unroll
        for (int cb = 0; cb < 2; cb++)
          acc[rb][cb] = __builtin_amdgcn_mfma_f32_32x32x16_f16(
              u, bu[ks * 2 + cb], acc[rb][cb], 0, 0, 0);
      }
    }
    if (m < 15) {
      wfu += 512;        // -> tile lk=2m+2
      loadB(bu, wfu);    // WAR on bu orders this after the MFMAs above
    }
    // ---- v-phase: consume bv (tile lk=2m+1) ----
#pragma unroll
    for (int ks = 0; ks < 2; ks++) {
      const int d0 = dBase + ks * 16 + q * 8;
      f16x8 eb = *(const f16x8*)(ejp + d0);
#pragma unroll
      for (int rb = 0; rb < 4; rb++) {
        f16x8 ea = *(const f16x8*)(eip + rb * 1040 + d0);
        f16x8 dd = ea - eb;
        f16x8 vv = __builtin_elementwise_max(dd, -dd);  // v_pk_max_f16
#pragma unroll
        for (int cb = 0; cb < 2; cb++)
          acc[rb][cb] = __builtin_amdgcn_mfma_f32_32x32x16_f16(
              vv, bv[ks * 2 + cb], acc[rb][cb], 0, 0, 0);
      }
    }
    if (m < 15) {
      wfv += 512;        // -> tile lk=2m+3
      loadB(bv, wfv);
    }
  }

  // ---- epilogue: emit fwd (i,j) and transposed (j,i) partial scores ----
  __syncthreads();  // e-tiles dead beyond this point; LDS re-used
  {
    float b1v = b1[ch0 + tid];
    for (int j = 0; j < 16; j++) {
      int grow = (bb * 256 + bj0 + j) * 512 + ch0 + tid;
      *(float*)(smem + CJB_OFF + (j * 256 + tid) * 4) = Cw[grow] + b1v;
      *(float*)(smem + AJB_OFF + (j * 256 + tid) * 4) = Aw[grow] + b1v;
    }
    *(float*)(smem + W2S_OFF + tid * 4) = w2[ch0 + tid];
  }
  __syncthreads();

  float* RED = (float*)(smem + RED_OFF);
  float* RED2 = (float*)(smem + RED2_OFF);
  const float* CJB = (const float*)(smem + CJB_OFF);
  const float* AJB = (const float*)(smem + AJB_OFF);
  const float* W2S = (const float*)(smem + W2S_OFF);
  // all loops touching acc force-unrolled -> static acc indices (rule #20)
#pragma unroll
  for (int rb = 0; rb < 4; rb++) {
    float av2[2][2], civ[2][2], w2v[2];
    int chls[2];
#pragma unroll
    for (int cb = 0; cb < 2; cb++) {
      int chl = wid * 64 + cb * 32 + n;
      chls[cb] = chl;
      w2v[cb] = W2S[chl];
      int irow = (bb * 256 + bi0 + rb * 2) * 512 + ch0 + chl;
      av2[cb][0] = Aw[irow];
      av2[cb][1] = Aw[irow + 512];
      civ[cb][0] = Cw[irow];
      civ[cb][1] = Cw[irow + 512];
    }
#pragma unroll
    for (int r = 0; r < 16; r++) {
      int rowl = (r & 3) + 8 * (r >> 2) + 4 * q;  // C/D layout (m74/m101)
      int j = rowl & 15;
      int hi = r >> 3;  // i-row parity within the rb pair
      float vf = 0.f, vt = 0.f;
#pragma unroll
      for (int cb = 0; cb < 2; cb++) {
        float base = acc[rb][cb][r];
        float hf = base + av2[cb][hi] + CJB[j * 256 + chls[cb]];
        if (hf > 0.f) vf += hf * w2v[cb];
        float ht = base + civ[cb][hi] + AJB[j * 256 + chls[cb]];
        if (ht > 0.f) vt += ht * w2v[cb];
      }
      vf += __shfl_xor(vf, 1); vt += __shfl_xor(vt, 1);
      vf += __shfl_xor(vf, 2); vt += __shfl_xor(vt, 2);
      vf += __shfl_xor(vf, 4); vt += __shfl_xor(vt, 4);
      vf += __shfl_xor(vf, 8); vt += __shfl_xor(vt, 8);
      if ((n & 15) == 0) {
        int p = (rb * 2 + hi) * 16 + j;  // pair index i*16+j
        int slot = p * 9 + wid * 2 + (n >> 4);
        RED[slot] = vf;
        RED2[slot] = vt;
      }
    }
  }

  __syncthreads();
  {
    int p = tid & 127;
    int gi = bi0 + (p >> 4), gj = bj0 + (p & 15);
    float half_b2 = 0.5f * b2[0];  // each ch-half block contributes half of b2
    if (tid < 128) {
      float s = half_b2;
      for (int u = 0; u < 8; u++) s += RED[p * 9 + u];
      if (gi <= gj) atomicAdd(out + (bb * 256 + gi) * 256 + gj, s);
    } else {
      float s = half_b2;
      for (int u = 0; u < 8; u++) s += RED2[p * 9 + u];
      if (gi < gj) atomicAdd(out + (bb * 256 + gj) * 256 + gi, s);
    }
  }
}

// ---------------- launcher ----------------
extern "C" void kernel_launch(void* const* d_in, const int* in_sizes, int n_in,
                              void* d_out, int out_size, void* d_ws, size_t ws_size,
                              hipStream_t stream) {
  const float* E = (const float*)d_in[0];
  const float* W1 = (const float*)d_in[1];
  const float* b1 = (const float*)d_in[2];
  const float* W2 = (const float*)d_in[3];
  const float* b2 = (const float*)d_in[4];
  float* out = (float*)d_out;
  char* ws = (char*)d_ws;
  u16* E16 = (u16*)(ws + WS_E16);
  u16* WT = (u16*)(ws + WS_WT);
  float* Aw = (float*)(ws + WS_A);
  float* Cw = (float*)(ws + WS_C);
  u16* WF = (u16*)(ws + WS_WF);

  // k_cvt also zeroes out (atomic-combine target) — no separate memset
  hipLaunchKernelGGL(k_cvt, dim3(768), dim3(256), 0, stream, E, E16, W1, WT, WF, out);
  hipLaunchKernelGGL(k_ac, dim3(16, 16), dim3(256), 0, stream, E16, WT, Aw, Cw);
  // 272 = # of 8x16 pair-tiles intersecting the upper triangle (tj*(tj+1)+ti)
  hipLaunchKernelGGL(k_pair, dim3(272, 2, 4), dim3(256), 0, stream,
                     E16, WF, Aw, Cw, b1, W2, b2, out);
}

// Round 5
// 224.790 us; speedup vs baseline: 1.5605x; 1.1473x over previous
//
#include <hip/hip_runtime.h>
#include <stdint.h>

typedef unsigned int u32;
typedef unsigned short u16;
typedef __attribute__((ext_vector_type(8))) _Float16 f16x8;
typedef __attribute__((ext_vector_type(16))) float f32x16;
typedef __attribute__((ext_vector_type(4))) float f32x4;

#define DEVI __device__ __forceinline__

// ---------------- numeric helpers ----------------
DEVI u16 f2h(float f) {  // f32 -> f16 RNE (v_cvt_f16_f32)
  _Float16 h = (_Float16)f;
  return __builtin_bit_cast(u16, h);
}

// ---------------- ws layout (bytes) ----------------
#define WS_E16 0             // f16 E, [1024 rows][512]
#define WS_WT (1u << 20)     // f16 W1^T, [512 ch][2048 k] (k_ac reads k<1024)
#define WS_A (3u << 20)      // f32 a = E@Wa
#define WS_C (5u << 20)      // f32 c = E@Wb
#define WS_WF (7u << 20)     // f16 Wc/Wd fragment-major, 1MB (k_pair B regs)

// ---------------- kernel 0: fused E->f16 + out-zeroing (blocks 0..511) and
//                  W1 (2048x512 f32) -> W16T (512x2048 f16) + WF fragment-major
//                  (blocks 512..767)
__global__ void k_cvt(const float* __restrict__ E, u16* __restrict__ E16,
                      const float* __restrict__ W1, u16* __restrict__ WT,
                      u16* __restrict__ WFo, float* __restrict__ outz) {
  __shared__ float tile[64][65];
  if (blockIdx.x < 512) {
    int i = (blockIdx.x * blockDim.x + threadIdx.x) * 4;
    float4 v = *(const float4*)(E + i);
    ushort4 o;
    o.x = f2h(v.x); o.y = f2h(v.y); o.z = f2h(v.z); o.w = f2h(v.w);
    *(ushort4*)(E16 + i) = o;
    // fold output zeroing (atomic-combine target): 256 blocks x 1024 floats
    if (blockIdx.x < 256) {
      float4 z; z.x = 0.f; z.y = 0.f; z.z = 0.f; z.w = 0.f;
      *(float4*)(outz + (blockIdx.x * blockDim.x + threadIdx.x) * 4) = z;
    }
    return;
  }
  int bid = blockIdx.x - 512;
  int t = threadIdx.x;
  int kBase = (bid & 31) * 64;   // 32 k-tiles
  int chBase = (bid >> 5) * 64;  // 8 ch-tiles
  int lr = t >> 4, lc = (t & 15) * 4;
  for (int rr = 0; rr < 4; rr++) {
    int kr = lr + rr * 16;
    float4 v = *(const float4*)(W1 + (kBase + kr) * 512 + chBase + lc);
    tile[kr][lc] = v.x; tile[kr][lc + 1] = v.y;
    tile[kr][lc + 2] = v.z; tile[kr][lc + 3] = v.w;
  }
  __syncthreads();
  int ch = t >> 2, ks = (t & 3) * 16;
  u32 w[8];
  for (int u = 0; u < 8; u++) {
    u16 lo = f2h(tile[ks + 2 * u][ch]);
    u16 hi = f2h(tile[ks + 2 * u + 1][ch]);
    w[u] = (u32)lo | ((u32)hi << 16);
  }
  u16* dst = WT + (chBase + ch) * 2048 + kBase + ks;
  uint4 s0; s0.x = w[0]; s0.y = w[1]; s0.z = w[2]; s0.w = w[3];
  uint4 s1; s1.x = w[4]; s1.y = w[5]; s1.z = w[6]; s1.w = w[7];
  *(uint4*)(dst) = s0;
  *(uint4*)(dst + 8) = s1;

  // ---- WF emission (Wc/Wd only): fragment-major layout so k_pair can load
  // B-fragments global->VGPR fully coalesced.
  // WF byte offset = ((cq*32 + lk)*4 + f)*1024 + lane*16, f = ks*2 + cb.
  // Fragment value = W1[k0 + kf + e][cq*64 + cb*32 + (lane&31)], e=0..7,
  // kf = (ks*2 + (lane>>5))*8 — identical halves to the old LDS bfr path.
  if (kBase >= 1024) {
    int fidx = (t >> 6) & 3;  // frag f
    int l = t & 63;           // lane
    int cbl = (fidx & 1) * 32 + (l & 31);
    int kf = ((fidx >> 1) * 2 + (l >> 5)) * 8;
    int cqv = bid >> 5;
#pragma unroll
    for (int s = 0; s < 2; s++) {
      int k0 = kBase + s * 32;  // == tile k-base of lk (verified mapping)
      int lk = (k0 < 1536) ? (((k0 - 1024) >> 5) * 2)
                           : (((k0 - 1536) >> 5) * 2 + 1);
      int klocal = s * 32 + kf;
      u32 wv[4];
#pragma unroll
      for (int u2 = 0; u2 < 4; u2++) {
        u16 lo = f2h(tile[klocal + 2 * u2][cbl]);
        u16 hi = f2h(tile[klocal + 2 * u2 + 1][cbl]);
        wv[u2] = (u32)lo | ((u32)hi << 16);
      }
      uint4 st; st.x = wv[0]; st.y = wv[1]; st.z = wv[2]; st.w = wv[3];
      *(uint4*)((char*)WFo + (((cqv * 32 + lk) * 4 + fidx) * 1024 + l * 16)) = st;
    }
  }
}

// ---------------- kernel 1: a = E@Wa, c = E@Wb (f16 MFMA) -------------------
// Retiled 64x64 (R10: 128x128 grid 8x8 = 64 blocks -> only 25% of CUs busy).
// grid 16x16 = 256 blocks, 8KB LDS, acc 16 AGPR/wave. K-chunk order identical
// to the 128-tile version -> bitwise-identical Aw/Cw.
__global__ __launch_bounds__(256) void k_ac(const u16* __restrict__ E16,
                                            const u16* __restrict__ WT,
                                            float* __restrict__ Aw,
                                            float* __restrict__ Cw) {
  __shared__ __align__(16) char smem[8192];
  char* sA = smem;         // [64 rows][32 k] f16, swizzled
  char* sB = smem + 4096;  // [64 ch][32 k]
  const int tid = threadIdx.x;
  const int lane = tid & 63, wid = tid >> 6;
  const int wr2 = wid >> 1, wc2 = wid & 1;  // wave quadrant of the 64x64 tile
  const int n = lane & 31, q = lane >> 5;
  const int rowBase = blockIdx.y * 64;
  const int chBase = blockIdx.x * 64;
  const int halfOff = (chBase >= 512) ? 512 : 0;
  const int chSrc0 = chBase - halfOff;
  f32x16 acc;
  for (int e = 0; e < 16; e++) acc[e] = 0.f;
  const int srow = tid >> 2, spg = tid & 3;
  const int slg = spg ^ ((srow >> 1) & 3);
  for (int kc = 0; kc < 16; kc++) {
    const int k0 = kc * 32;
    __syncthreads();
    *(uint4*)(sA + srow * 64 + slg * 16) =
        *(const uint4*)(E16 + (rowBase + srow) * 512 + k0 + spg * 8);
    *(uint4*)(sB + srow * 64 + slg * 16) =
        *(const uint4*)(WT + (chSrc0 + srow) * 2048 + halfOff + k0 + spg * 8);
    __syncthreads();
    for (int ks = 0; ks < 2; ks++) {
      int kg = ks * 2 + q;
      int row = wr2 * 32 + n;
      int ch = wc2 * 32 + n;
      f16x8 af = *(const f16x8*)(sA + row * 64 + ((kg ^ ((row >> 1) & 3)) * 16));
      f16x8 bf = *(const f16x8*)(sB + ch * 64 + ((kg ^ ((ch >> 1) & 3)) * 16));
      acc = __builtin_amdgcn_mfma_f32_32x32x16_f16(af, bf, acc, 0, 0, 0);
    }
  }
  for (int r = 0; r < 16; r++) {
    int rowl = (r & 3) + 8 * (r >> 2) + 4 * q;  // C/D layout (m74/m101)
    int rowg = rowBase + wr2 * 32 + rowl;
    int chg = chBase + wc2 * 32 + n;
    float v = acc[r];
    if (chg < 512) Aw[rowg * 512 + chg] = v;
    else Cw[rowg * 512 + chg - 512] = v;
  }
}

// ---------------- kernel 2: pair kernel (f16, operand-swapped MFMA) ---------
// R15: main loops of R0/R11/R13/R14 all landed at ~200us / MfmaUtil ~34 —
// the invariant cost is the EPILOGUE (512 shfl + 256 per-lane b32 LDS reads
// per wave = ~40-55us of serialized DS-pipe time), forced by the C/D layout
// (ch on lanes -> cross-lane ch-reduction). Fix (T12's idea): A and B operand
// layouts of 32x32x16 are the same (lane,reg)->(idx,k) map, so SWAPPING the
// MFMA arguments — mfma(W_frag, e_form, acc) — transposes D: pair = lane,
// ch = regs. Formation code, WF buffer, k-order: unchanged; acc values
// bitwise identical, transposed residency. The ch-reduction becomes a pure
// per-lane VALU loop + ONE shfl_xor(32) + one LDS slot write. Epilogue
// operands (a_i, c_i, c_j+b1, a_j+b1) staged in LDS, stride-266.. (264) pad.
#define EI_OFF 0             // 8 rows x 520 f16 (1040B) = 8320
#define EJ_OFF 8320          // 16 rows x 1040B = 16640 -> 24960
// epilogue overlays (e-region + beyond, after the post-main __syncthreads):
#define SI_OFF 0             // 16 rows x 264 f32: [0..7]=Aw_i, [8..15]=Cw_i
#define SJ_OFF 16896         // 32 rows x 264 f32: [0..15]=Cw_j+b1, [16..31]=Aw_j+b1
#define W2S_OFF 50688        // 256 f32 -> 51712
#define RED_OFF 51712        // 128 pairs x 5 slots f32 -> 54272
#define RED2_OFF 54272       // -> 56832
#define SMEM2 56832

// acc[4][2]=128 AGPR + bu/bv 32 + ~80 arch VGPR <= 256: 2 waves/SIMD max.
__global__ __launch_bounds__(256, 2) void k_pair(
    const u16* __restrict__ E16, const u16* __restrict__ WF,
    const float* __restrict__ Aw, const float* __restrict__ Cw,
    const float* __restrict__ b1, const float* __restrict__ w2,
    const float* __restrict__ b2, float* __restrict__ out) {
  __shared__ __align__(16) char smem[SMEM2];
  const int tid = threadIdx.x;
  const int lane = tid & 63, wid = tid >> 6;  // wid = ch-quarter owner
  const int n = lane & 31, q = lane >> 5;
  const int bb = blockIdx.z;
  const int ch0 = blockIdx.y * 256;

  // invert triangular tile index: f = tj*(tj+1) + ti, ti in [0, 2*tj+2)
  int f = blockIdx.x;
  int tj = (int)((__builtin_sqrtf(4.0f * (float)f + 1.0f) - 1.0f) * 0.5f);
  while ((tj + 1) * (tj + 2) <= f) tj++;
  while (tj * (tj + 1) > f) tj--;
  const int ti = f - tj * (tj + 1);
  const int bi0 = ti * 8;
  const int bj0 = tj * 16;

  // fragment-major B pointer for this wave's exclusive 64-ch chunk
  const int cq = blockIdx.y * 4 + wid;  // ch-quarter 0..7
  const f16x8* wfp = (const f16x8*)WF + cq * 8192 + lane;
  const f16x8* wfu = wfp;        // tile lk=0
  const f16x8* wfv = wfp + 256;  // tile lk=1

  f16x8 bu[4], bv[4];  // frag f = ks*2 + cb
  auto loadB = [&](f16x8 (&b)[4], const f16x8* p) {
#pragma unroll
    for (int f2 = 0; f2 < 4; f2++) b[f2] = p[f2 * 64];  // imm offsets 0..3KB
  };

  loadB(bu, wfu);  // tile 0 in flight

  // stage e-tiles f16 (rows 0..7 = e_i, 8..23 = e_j), 520-elem stride
  for (int s = tid; s < 1536; s += 256) {
    int row = s >> 6, c16 = s & 63;
    int grow = (row < 8) ? (bi0 + row) : (bj0 + row - 8);
    const u16* src = E16 + (bb * 256 + grow) * 512 + c16 * 8;
    int off = (row < 8) ? (EI_OFF + (row * 520 + c16 * 8) * 2)
                        : (EJ_OFF + ((row - 8) * 520 + c16 * 8) * 2);
    *(uint4*)(smem + off) = *(const uint4*)src;
  }
  __syncthreads();  // e-tiles visible to all waves
  loadB(bv, wfv);   // tile 1 in flight

  // lane n owns pairs (i = 2rb + (n>>4), j = n&15); k-half by q
  const u16* eip = (const u16*)(smem + EI_OFF) + (n >> 4) * 520;
  const u16* ejp = (const u16*)(smem + EJ_OFF) + (n & 15) * 520;

  f32x16 acc[4][2];
#pragma unroll
  for (int a = 0; a < 4; a++)
#pragma unroll
    for (int c = 0; c < 2; c++)
#pragma unroll
      for (int e = 0; e < 16; e++) acc[a][c][e] = 0.f;

  for (int m = 0; m < 16; m++) {
    const int dBase = m * 32;
    // ---- u-phase: consume bu (tile lk=2m) ----
#pragma unroll
    for (int ks = 0; ks < 2; ks++) {
      const int d0 = dBase + ks * 16 + q * 8;
      f16x8 eb = *(const f16x8*)(ejp + d0);
#pragma unroll
      for (int rb = 0; rb < 4; rb++) {
        f16x8 ea = *(const f16x8*)(eip + rb * 1040 + d0);  // rows (n>>4)+2rb
        f16x8 u = ea * eb;  // v_pk_mul_f16
#pragma unroll
        for (int cb = 0; cb < 2; cb++)
          acc[rb][cb] = __builtin_amdgcn_mfma_f32_32x32x16_f16(
              bu[ks * 2 + cb], u, acc[rb][cb], 0, 0, 0);  // SWAPPED args
      }
    }
    if (m < 15) {
      wfu += 512;        // -> tile lk=2m+2
      loadB(bu, wfu);    // WAR on bu orders this after the MFMAs above
    }
    // ---- v-phase: consume bv (tile lk=2m+1) ----
#pragma unroll
    for (int ks = 0; ks < 2; ks++) {
      const int d0 = dBase + ks * 16 + q * 8;
      f16x8 eb = *(const f16x8*)(ejp + d0);
#pragma unroll
      for (int rb = 0; rb < 4; rb++) {
        f16x8 ea = *(const f16x8*)(eip + rb * 1040 + d0);
        f16x8 dd = ea - eb;
        f16x8 vv = __builtin_elementwise_max(dd, -dd);  // v_pk_max_f16
#pragma unroll
        for (int cb = 0; cb < 2; cb++)
          acc[rb][cb] = __builtin_amdgcn_mfma_f32_32x32x16_f16(
              bv[ks * 2 + cb], vv, acc[rb][cb], 0, 0, 0);  // SWAPPED args
      }
    }
    if (m < 15) {
      wfv += 512;        // -> tile lk=2m+3
      loadB(bv, wfv);
    }
  }

  // ---- epilogue (R15): acc transposed -> per-lane ch reduction -----------
  // acc[rb][cb][r]: pair (i = 2rb+(n>>4), j = n&15), ch (within y-half) =
  // wid*64 + cb*32 + (r&3) + 8*(r>>2) + 4*q.
  __syncthreads();  // e-tiles dead; overlay epilogue arrays
  float* SIp = (float*)(smem + SI_OFF);
  float* SJp = (float*)(smem + SJ_OFF);
  float* W2Sp = (float*)(smem + W2S_OFF);
  float* RED = (float*)(smem + RED_OFF);
  float* RED2 = (float*)(smem + RED2_OFF);
  {
    float b1v = b1[ch0 + tid];
    for (int ii = 0; ii < 8; ii++) {
      int gri = (bb * 256 + bi0 + ii) * 512 + ch0 + tid;
      SIp[ii * 264 + tid] = Aw[gri];
      SIp[(8 + ii) * 264 + tid] = Cw[gri];
    }
    for (int jj = 0; jj < 16; jj++) {
      int grj = (bb * 256 + bj0 + jj) * 512 + ch0 + tid;
      SJp[jj * 264 + tid] = Cw[grj] + b1v;
      SJp[(16 + jj) * 264 + tid] = Aw[grj] + b1v;
    }
    W2Sp[tid] = w2[ch0 + tid];
  }
  __syncthreads();

  const int jrow = n & 15, ihalf = n >> 4;
#pragma unroll
  for (int rb = 0; rb < 4; rb++) {
    const int irow = rb * 2 + ihalf;
    float vfa = 0.f, vta = 0.f;
#pragma unroll
    for (int cb = 0; cb < 2; cb++) {
#pragma unroll
      for (int g = 0; g < 4; g++) {
        const int chl = wid * 64 + cb * 32 + 8 * g + 4 * q;
        f32x4 ai = *(const f32x4*)(SIp + irow * 264 + chl);         // Aw[i]
        f32x4 ci = *(const f32x4*)(SIp + (8 + irow) * 264 + chl);   // Cw[i]
        f32x4 cj = *(const f32x4*)(SJp + jrow * 264 + chl);         // Cw[j]+b1
        f32x4 aj = *(const f32x4*)(SJp + (16 + jrow) * 264 + chl);  // Aw[j]+b1
        f32x4 wv = *(const f32x4*)(W2Sp + chl);
#pragma unroll
        for (int t = 0; t < 4; t++) {
          float base = acc[rb][cb][g * 4 + t];
          float hf = base + ai[t] + cj[t];   // h(i,j)
          if (hf > 0.f) vfa += hf * wv[t];
          float ht = base + ci[t] + aj[t];   // h(j,i)
          if (ht > 0.f) vta += ht * wv[t];
        }
      }
    }
    // q-halves hold complementary ch sets of the same pair: one swap-add
    vfa += __shfl_xor(vfa, 32);
    vta += __shfl_xor(vta, 32);
    int p = irow * 16 + jrow;
    if (q == 0) RED[p * 5 + wid] = vfa;
    else        RED2[p * 5 + wid] = vta;
  }

  __syncthreads();
  {
    int p = tid & 127;
    int gi = bi0 + (p >> 4), gj = bj0 + (p & 15);
    float half_b2 = 0.5f * b2[0];  // each ch-half block contributes half of b2
    if (tid < 128) {
      float s = half_b2;
      for (int u = 0; u < 4; u++) s += RED[p * 5 + u];
      if (gi <= gj) atomicAdd(out + (bb * 256 + gi) * 256 + gj, s);
    } else {
      float s = half_b2;
      for (int u = 0; u < 4; u++) s += RED2[p * 5 + u];
      if (gi < gj) atomicAdd(out + (bb * 256 + gj) * 256 + gi, s);
    }
  }
}

// ---------------- launcher ----------------
extern "C" void kernel_launch(void* const* d_in, const int* in_sizes, int n_in,
                              void* d_out, int out_size, void* d_ws, size_t ws_size,
                              hipStream_t stream) {
  const float* E = (const float*)d_in[0];
  const float* W1 = (const float*)d_in[1];
  const float* b1 = (const float*)d_in[2];
  const float* W2 = (const float*)d_in[3];
  const float* b2 = (const float*)d_in[4];
  float* out = (float*)d_out;
  char* ws = (char*)d_ws;
  u16* E16 = (u16*)(ws + WS_E16);
  u16* WT = (u16*)(ws + WS_WT);
  float* Aw = (float*)(ws + WS_A);
  float* Cw = (float*)(ws + WS_C);
  u16* WF = (u16*)(ws + WS_WF);

  // k_cvt also zeroes out (atomic-combine target) — no separate memset
  hipLaunchKernelGGL(k_cvt, dim3(768), dim3(256), 0, stream, E, E16, W1, WT, WF, out);
  hipLaunchKernelGGL(k_ac, dim3(16, 16), dim3(256), 0, stream, E16, WT, Aw, Cw);
  // 272 = # of 8x16 pair-tiles intersecting the upper triangle (tj*(tj+1)+ti)
  hipLaunchKernelGGL(k_pair, dim3(272, 2, 4), dim3(256), 0, stream,
                     E16, WF, Aw, Cw, b1, W2, b2, out);
}